// Round 9
// baseline (266.237 us; speedup 1.0000x reference)
//
#include <hip/hip_runtime.h>
#include <hip/hip_bf16.h>
#include <math.h>

// Problem constants
#define Bn  2
#define Nn  512
#define Dn  128
#define FHn 512
#define BND (Bn*Nn*Dn)   // 131072

typedef __hip_bfloat16 bf16;

__device__ __forceinline__ float cvt(float x) { return x; }
__device__ __forceinline__ float cvt(bf16 x) { return __bfloat162float(x); }
__device__ __forceinline__ float sigmoidf_(float x) { return 1.0f / (1.0f + expf(-x)); }
__device__ __forceinline__ bool is_bf16(const void* alpha) {
    return ((const unsigned short*)alpha)[0] == 0x3F80;
}

// ---------------------------------------------------------------------------
// Workspace layout (float offsets). S = one (B,N,D) f32 slab.
// eK/eKV are stored TRANSPOSED: [b*128+h][j] (col-major vs token axis) so
// k_kekv writes coalesced and k_attn reads contiguous float4 per thread.
#define S_ 131072
#define WS_Q    (0 * S_)
#define WS_K    (1 * S_)
#define WS_V    (2 * S_)
#define WS_EK   (3 * S_)
#define WS_EKV  (4 * S_)
#define WS_EAB  (5 * S_)   // (B,N,N) f32 = 4 slabs
#define WS_MH   (1 * S_)
#define WS_T    (2 * S_)
#define WS_OP   (3 * S_)
#define WS_ST   (9 * S_)

// stats region (float offsets inside WS_ST)
#define ST_IN_SC   0      // 512: [which*256 + b*128 + d]
#define ST_IN_SH   512
#define ST_X_SC    2048
#define ST_X_SH    2304
#define ST_PRE     3072
#define P_SC       1024   // cds, cdt, cas, cat, gate_b, outlin_b, alpha (7)
#define ST_TAB     4224   // 1288 floats of piecewise-linear tables

// Table layout (relative to ST_TAB); dist at 0, angle at +644.
#define TAB_ANG 644
#define TAB_N   1288

#define SMEM_FLOATS 2568   // 2560 work + 8 reduce scratch

struct KP {
    const void *row, *col, *cost, *coords, *alpha;
    const void *n1w, *n1b, *n2w, *n2b, *n3w, *n3b, *f1w, *f1b, *f2w, *f2b;
    const void *qw, *qb, *kw, *kb, *vw, *vb, *pw, *pb, *mw, *mb;
    const void *dw1, *db1, *dw2, *db2, *aw1, *ab1, *aw2, *ab2, *gw, *gb, *ow, *ob;
    const void *ffw1, *ffb1, *ffw2, *ffb2;
    void* out;
    float* ws;
};

// ---------------------------------------------------------------------------
// Block-level reductions (256 threads). scr >= 8 floats. All threads get result.
__device__ __forceinline__ void blk_sum2(float& s, float& ss, volatile float* scr) {
#pragma unroll
    for (int off = 32; off > 0; off >>= 1) { s += __shfl_down(s, off); ss += __shfl_down(ss, off); }
    __syncthreads();
    int wave = threadIdx.x >> 6, lane = threadIdx.x & 63;
    if (lane == 0) { scr[wave] = s; scr[4 + wave] = ss; }
    __syncthreads();
    s = scr[0] + scr[1] + scr[2] + scr[3];
    ss = scr[4] + scr[5] + scr[6] + scr[7];
}

__device__ __forceinline__ float blk_sum1(float v, volatile float* scr) {
#pragma unroll
    for (int off = 32; off > 0; off >>= 1) v += __shfl_down(v, off);
    __syncthreads();
    int wave = threadIdx.x >> 6, lane = threadIdx.x & 63;
    if (lane == 0) scr[wave] = v;
    __syncthreads();
    return scr[0] + scr[1] + scr[2] + scr[3];
}

__device__ __forceinline__ float blk_max1(float v, volatile float* scr) {
#pragma unroll
    for (int off = 32; off > 0; off >>= 1) v = fmaxf(v, __shfl_down(v, off));
    __syncthreads();
    int wave = threadIdx.x >> 6, lane = threadIdx.x & 63;
    if (lane == 0) scr[wave] = v;
    __syncthreads();
    return fmaxf(fmaxf(scr[0], scr[1]), fmaxf(scr[2], scr[3]));
}

// ---------------------------------------------------------------------------
// Build piecewise-linear tables for one scalar MLP — fully parallel (R8).
template <typename T>
__device__ void build_tables(const T* w1p, const T* b1p, const T* w2p,
                             const T* owp, const T* gwp, float* gtab, float* smem) {
    int tid = threadIdx.x;
    float* W  = smem;          // 128
    float* Bb = smem + 128;
    float* U  = smem + 256;
    float* Vv = smem + 384;
    float* Tt = smem + 512;
    int* RK   = (int*)(smem + 640);   // 128 ranks
    if (tid < 128) {
        float u = 0.f, v = 0.f;
#pragma unroll 4
        for (int d = 0; d < Dn; ++d) {
            float w2 = cvt(w2p[tid * Dn + d]);
            u += w2 * cvt(owp[d]);
            v += w2 * cvt(gwp[d]);
        }
        float w = cvt(w1p[tid]), b = cvt(b1p[tid]);
        U[tid] = u; Vv[tid] = v; W[tid] = w; Bb[tid] = b;
        Tt[tid] = (w != 0.f) ? (-b / w) : 3.0e38f;
    }
    __syncthreads();
    if (tid < 128) {
        float tk = Tt[tid]; int r = 0;
        for (int j = 0; j < 128; ++j) {
            float tj = Tt[j];
            r += (tj < tk) || (tj == tk && j < tid);
        }
        RK[tid] = r;
        gtab[r] = tk;        // sorted breakpoint table (scatter by rank)
    }
    __syncthreads();
    if (tid <= 128) {
        int si = tid;
        float slS = 0, inS = 0, slT = 0, inT = 0;
        for (int k = 0; k < 128; ++k) {
            float w = W[k];
            if (w == 0.f) {
                float rb = fmaxf(Bb[k], 0.f);
                inS += rb * U[k];
                inT += rb * Vv[k];
            } else {
                bool act = (w > 0.f) ? (RK[k] < si) : (RK[k] >= si);
                if (act) {
                    slS += w * U[k];  inS += Bb[k] * U[k];
                    slT += w * Vv[k]; inT += Bb[k] * Vv[k];
                }
            }
        }
        gtab[128 + si] = slS;
        gtab[257 + si] = inS;
        gtab[386 + si] = slT;
        gtab[515 + si] = inT;
    }
}

// number of sorted breakpoints <= c, in [0,128]; 8 uniform iterations.
__device__ __forceinline__ int bsearch128(const float* T, float c) {
    int lo = 0, hi = 128;
    while (lo < hi) { int mid = (lo + hi) >> 1; if (T[mid] <= c) lo = mid + 1; else hi = mid; }
    return lo;
}

// ---------------------------------------------------------------------------
// Phase 0: input instance-norm stats (512 cols, 1/block); block 128 = scalar
// constants; blocks 129/130 = dist/angle piecewise tables.
template <typename T>
__device__ void phase0(const KP& p, float* st, float* smem) {
    float* scr = smem + 2560;
    int cid = blockIdx.x;    // 0..511
    int tid = threadIdx.x;
    {
        int which = cid >> 8, b = (cid >> 7) & 1, d = cid & 127;
        const T* src = (const T*)(which ? p.col : p.row) + (size_t)b * Nn * Dn + d;
        float x0 = cvt(src[(size_t)tid * Dn]);
        float x1 = cvt(src[(size_t)(tid + 256) * Dn]);
        float s = x0 + x1, ss = x0 * x0 + x1 * x1;
        blk_sum2(s, ss, scr);
        if (tid == 0) {
            float m = s * (1.f / Nn);
            float v = fmaxf(ss * (1.f / Nn) - m * m, 0.f);
            float rstd = rsqrtf(v + 1e-5f);
            const T* w = which ? (const T*)p.n2w : (const T*)p.n1w;
            const T* bb = which ? (const T*)p.n2b : (const T*)p.n1b;
            float sc = rstd * cvt(w[d]);
            st[ST_IN_SC + cid] = sc;
            st[ST_IN_SH + cid] = cvt(bb[d]) - m * sc;
        }
    }
    __syncthreads();
    if (cid == 128) {
        const T* db2 = (const T*)p.db2; const T* ab2 = (const T*)p.ab2;
        const T* ow = (const T*)p.ow;   const T* gw = (const T*)p.gw;
        float d2 = 0.f, a2 = 0.f, o = 0.f, g0 = 0.f, g1 = 0.f;
        if (tid < 128) {
            d2 = cvt(db2[tid]); a2 = cvt(ab2[tid]);
            o = cvt(ow[tid]); g0 = cvt(gw[tid]); g1 = cvt(gw[Dn + tid]);
        }
        float cds = d2 * o, cdt = d2 * g0, cas = a2 * o, cat = a2 * g1;
        blk_sum2(cds, cdt, scr);
        blk_sum2(cas, cat, scr);
        if (tid == 0) {
            float* pre = st + ST_PRE;
            pre[P_SC + 0] = cds; pre[P_SC + 1] = cdt;
            pre[P_SC + 2] = cas; pre[P_SC + 3] = cat;
            pre[P_SC + 4] = cvt(((const T*)p.gb)[0]);
            pre[P_SC + 5] = cvt(((const T*)p.ob)[0]);
            pre[P_SC + 6] = cvt(((const T*)p.alpha)[0]);
        }
    } else if (cid == 129) {
        build_tables<T>((const T*)p.dw1, (const T*)p.db1, (const T*)p.dw2,
                        (const T*)p.ow, (const T*)p.gw, st + ST_TAB, smem);
    } else if (cid == 130) {
        build_tables<T>((const T*)p.aw1, (const T*)p.ab1, (const T*)p.aw2,
                        (const T*)p.ow, (const T*)p.gw + Dn, st + ST_TAB + TAB_ANG, smem);
    }
}

// ---------------------------------------------------------------------------
// Phase 1: QKV for 2 rows/block, then eab (table-based) for the same 2 rows.
template <typename T>
__device__ void phase1(const KP& p, float* st, float* smem) {
    int tid = threadIdx.x;
    int r0 = blockIdx.x * 2;     // rows r0, r0+1  (0..1023)
    int b = r0 >> 9;
    const T* row = (const T*)p.row; const T* col = (const T*)p.col;
    float* ws = p.ws;
    float* Q = ws + WS_Q; float* Kraw = ws + WS_K; float* V = ws + WS_V;

    // --- QKV ---
    float* lr = smem;            // [2][128]
    float* lc = smem + 256;      // [2][128]
    float* redq = smem + 512;    // [2(half)][2(row)][128]
    float* redk = smem + 1024;
    float* redv = smem + 1536;
    {
        int r = tid >> 7, d = tid & 127;
        float scR = st[ST_IN_SC + b * 128 + d],       shR = st[ST_IN_SH + b * 128 + d];
        float scC = st[ST_IN_SC + 256 + b * 128 + d], shC = st[ST_IN_SH + 256 + b * 128 + d];
        lr[r * 128 + d] = cvt(row[(size_t)(r0 + r) * Dn + d]) * scR + shR;
        lc[r * 128 + d] = cvt(col[(size_t)(r0 + r) * Dn + d]) * scC + shC;
    }
    __syncthreads();
    {
        int h = tid & 127, half = tid >> 7;
        const T* qw = (const T*)p.qw; const T* kw = (const T*)p.kw; const T* vw = (const T*)p.vw;
        float q0 = 0, q1 = 0, ka = 0, kb_ = 0, v0 = 0, v1 = 0;
        int ks = half * 64;
#pragma unroll 8
        for (int k = ks; k < ks + 64; ++k) {
            float wq = cvt(qw[k * Dn + h]);
            float wk = cvt(kw[k * Dn + h]);
            float wv = cvt(vw[k * Dn + h]);
            q0 += lr[k] * wq;        q1 += lr[128 + k] * wq;
            ka += lc[k] * wk;        kb_ += lc[128 + k] * wk;
            v0 += lc[k] * wv;        v1 += lc[128 + k] * wv;
        }
        redq[half * 256 + h] = q0;  redq[half * 256 + 128 + h] = q1;
        redk[half * 256 + h] = ka;  redk[half * 256 + 128 + h] = kb_;
        redv[half * 256 + h] = v0;  redv[half * 256 + 128 + h] = v1;
    }
    __syncthreads();
    if (tid < 128) {
        int h = tid;
        float bq = cvt(((const T*)p.qb)[h]);
        float bk = cvt(((const T*)p.kb)[h]);
        float bv = cvt(((const T*)p.vb)[h]);
#pragma unroll
        for (int r = 0; r < 2; ++r) {
            Q[(r0 + r) * Dn + h]    = sigmoidf_(redq[r * 128 + h] + redq[256 + r * 128 + h] + bq);
            Kraw[(r0 + r) * Dn + h] = redk[r * 128 + h] + redk[256 + r * 128 + h] + bk;
            V[(r0 + r) * Dn + h]    = redv[r * 128 + h] + redv[256 + r * 128 + h] + bv;
        }
    }
    __syncthreads();

    // --- eab via piecewise-linear tables ---
    float* abv = smem;           // [512]
    float* red = smem + 512;     // [256]
    float* tab = smem + 768;     // [1288]
    const float* gtab = st + ST_TAB;
    for (int e = tid; e < TAB_N; e += 256) tab[e] = gtab[e];
    __syncthreads();
    float* eab = ws + WS_EAB;
    const float* pre = st + ST_PRE;
    float cds = pre[P_SC + 0], cdt = pre[P_SC + 1], cas = pre[P_SC + 2], cat = pre[P_SC + 3];
    float gbias = pre[P_SC + 4], obias = pre[P_SC + 5], alpha = pre[P_SC + 6];
    const T* cost = (const T*)p.cost;
    const T* coords = (const T*)p.coords;

    for (int rr = 0; rr < 2; ++rr) {
        int rowi = r0 + rr;
        int bb_ = rowi >> 9, i = rowi & 511;
        float cix = cvt(coords[((size_t)bb_ * Nn + i) * 2 + 0]);
        float ciy = cvt(coords[((size_t)bb_ * Nn + i) * 2 + 1]);
        const T* crow = cost + (size_t)bb_ * Nn * Nn + (size_t)i * Nn;
#pragma unroll
        for (int jj = 0; jj < 2; ++jj) {
            int j = tid + jj * 256;
            float c = cvt(crow[j]);
            int si = bsearch128(tab, c);
            float sd = fmaf(tab[128 + si], c, tab[257 + si]) + cds;
            float td = fmaf(tab[386 + si], c, tab[515 + si]) + cdt;
            float dx = cix - cvt(coords[((size_t)bb_ * Nn + j) * 2 + 0]);
            float dy = ciy - cvt(coords[((size_t)bb_ * Nn + j) * 2 + 1]);
            float ang = (dx == 0.f && dy == 0.f) ? 0.f : atan2f(dy, dx);
            int ai = bsearch128(tab + TAB_ANG, ang);
            float sa = fmaf(tab[TAB_ANG + 128 + ai], ang, tab[TAB_ANG + 257 + ai]) + cas;
            float ta = fmaf(tab[TAB_ANG + 386 + ai], ang, tab[TAB_ANG + 515 + ai]) + cat;
            float gv = sigmoidf_(td + ta + gbias);
            abv[j] = alpha * (gv * sd + (1.f - gv) * sa + obias);
        }
        __syncthreads();
        float m = fmaxf(abv[tid], abv[tid + 256]);
        red[tid] = m; __syncthreads();
        for (int s = 128; s > 0; s >>= 1) {
            if (tid < s) red[tid] = fmaxf(red[tid], red[tid + s]);
            __syncthreads();
        }
        m = red[0];
        __syncthreads();
        float e0 = expf(abv[tid] - m), e1 = expf(abv[tid + 256] - m);
        red[tid] = e0 + e1; __syncthreads();
        for (int s = 128; s > 0; s >>= 1) {
            if (tid < s) red[tid] += red[tid + s];
            __syncthreads();
        }
        float rsum = 1.f / red[0];
        float* orow = eab + (size_t)rowi * Nn;
        orow[tid] = expf(e0 * rsum);
        orow[tid + 256] = expf(e1 * rsum);
        __syncthreads();
    }
}

// ---------------------------------------------------------------------------
// Phase 2: K-softmax over tokens + fused eK/eKV in TRANSPOSED [c][j] layout.
// 256 blocks, 1 col each. Writes are now fully coalesced.
__device__ void phase2(const KP& p, float* smem) {
    float* scr = smem + 2560;
    int tid = threadIdx.x;
    int c = blockIdx.x;          // 0..255 == b*128+h
    int b = c >> 7, h = c & 127;
    float* ws = p.ws;
    const float* Kraw = ws + WS_K;
    const float* V = ws + WS_V;
    float* eKt = ws + WS_EK;     // [c][512]
    float* eKVt = ws + WS_EKV;   // [c][512]
    const float* kb = Kraw + (size_t)b * Nn * Dn + h;
    const float* vb = V + (size_t)b * Nn * Dn + h;
    float x0 = kb[(size_t)tid * Dn];
    float x1 = kb[(size_t)(tid + 256) * Dn];
    float mx = blk_max1(fmaxf(x0, x1), scr);
    float e0 = expf(x0 - mx), e1 = expf(x1 - mx);
    float s = blk_sum1(e0 + e1, scr);
    float rs = 1.f / s;
    float ek0 = expf(e0 * rs), ek1 = expf(e1 * rs);
    float* ekr = eKt + (size_t)c * 512;
    float* evr = eKVt + (size_t)c * 512;
    ekr[tid] = ek0;        evr[tid] = ek0 * vb[(size_t)tid * Dn];
    ekr[tid + 256] = ek1;  evr[tid + 256] = ek1 * vb[(size_t)(tid + 256) * Dn];
}

// ---------------------------------------------------------------------------
// Phase 3: num/den einsums (transposed eK/eKV, float4 streams; G in LDS) +
// p/mhc projections. 2 rows/block, 512 blocks.
template <typename T>
__device__ void phase3(const KP& p, float* smem) {
    int tid = threadIdx.x;
    int r0 = blockIdx.x * 2;
    int b = r0 >> 9;
    float* ws = p.ws;
    const float* eab = ws + WS_EAB;
    const float* eKt = ws + WS_EK;    // [b*128+h][512]
    const float* eKVt = ws + WS_EKV;
    const float* Q = ws + WS_Q;
    float* mh = ws + WS_MH;

    float* ab   = smem;          // [2][512]
    float* redn = smem + 1024;   // [2][2][128]
    float* redd = smem + 1536;   // [2][2][128]
    float* gl   = smem + 2048;   // [2][128]
    float* yl   = smem + 2304;   // [2][128]

    {   // vectorized eab stage: 256 threads x float4 == 1024 floats
        float4* ab4 = (float4*)ab;
        const float4* g4 = (const float4*)(eab + (size_t)r0 * Nn);
        ab4[tid] = g4[tid];
    }
    __syncthreads();
    int h = tid & 127, half = tid >> 7;
    {
        float n0 = 0, n1 = 0, d0 = 0, d1 = 0;
        int j0 = half * 256;
        const float4* ek4 = (const float4*)(eKt + ((size_t)(b * 128 + h)) * 512 + j0);
        const float4* ev4 = (const float4*)(eKVt + ((size_t)(b * 128 + h)) * 512 + j0);
        const float4* a04 = (const float4*)(ab + j0);
        const float4* a14 = (const float4*)(ab + 512 + j0);
#pragma unroll 4
        for (int q = 0; q < 64; ++q) {
            float4 ek = ek4[q];
            float4 ev = ev4[q];
            float4 a0 = a04[q];
            float4 a1 = a14[q];
            n0 += a0.x * ev.x + a0.y * ev.y + a0.z * ev.z + a0.w * ev.w;
            d0 += a0.x * ek.x + a0.y * ek.y + a0.z * ek.z + a0.w * ek.w;
            n1 += a1.x * ev.x + a1.y * ev.y + a1.z * ev.z + a1.w * ev.w;
            d1 += a1.x * ek.x + a1.y * ek.y + a1.z * ek.z + a1.w * ek.w;
        }
        redn[half * 256 + h] = n0;  redn[half * 256 + 128 + h] = n1;
        redd[half * 256 + h] = d0;  redd[half * 256 + 128 + h] = d1;
    }
    __syncthreads();
    if (tid < 128) {
#pragma unroll
        for (int r = 0; r < 2; ++r) {
            float nu = redn[r * 128 + h] + redn[256 + r * 128 + h];
            float de = redd[r * 128 + h] + redd[256 + r * 128 + h];
            gl[r * 128 + h] = Q[(r0 + r) * Dn + h] * nu / de;
        }
    }
    __syncthreads();
    {
        const T* pw = (const T*)p.pw;
        float a0 = 0, a1 = 0;
        int ks = half * 64;
#pragma unroll 8
        for (int k = ks; k < ks + 64; ++k) {
            float w = cvt(pw[k * Dn + h]);
            a0 += gl[k] * w;
            a1 += gl[128 + k] * w;
        }
        redn[half * 256 + h] = a0;  redn[half * 256 + 128 + h] = a1;
    }
    __syncthreads();
    if (tid < 128) {
        float bp = cvt(((const T*)p.pb)[h]);
        yl[h] = redn[h] + redn[256 + h] + bp;
        yl[128 + h] = redn[128 + h] + redn[256 + 128 + h] + bp;
    }
    __syncthreads();
    {
        const T* mw = (const T*)p.mw;
        float a0 = 0, a1 = 0;
        int ks = half * 64;
#pragma unroll 8
        for (int k = ks; k < ks + 64; ++k) {
            float w = cvt(mw[k * Dn + h]);
            a0 += yl[k] * w;
            a1 += yl[128 + k] * w;
        }
        redn[half * 256 + h] = a0;  redn[half * 256 + 128 + h] = a1;
    }
    __syncthreads();
    if (tid < 128) {
        float bm = cvt(((const T*)p.mb)[h]);
        mh[(r0 + 0) * Dn + h] = redn[h] + redn[256 + h] + bm;
        mh[(r0 + 1) * Dn + h] = redn[128 + h] + redn[256 + 128 + h] + bm;
    }
}

// ---------------------------------------------------------------------------
// Phase 4+5 fused: per-column mh stats (local) -> t build -> x stats. 256 blocks.
template <typename T>
__device__ void phase45(const KP& p, float* st, float* smem) {
    float* scr = smem + 2560;
    int tid = threadIdx.x;
    int c = blockIdx.x;          // 0..255
    int b = c >> 7, d = c & 127;
    const float* mh = p.ws + WS_MH;
    const float* mp = mh + (size_t)b * Nn * Dn + d;
    float m0 = mp[(size_t)tid * Dn], m1 = mp[(size_t)(tid + 256) * Dn];
    float s = m0 + m1, ss = m0 * m0 + m1 * m1;
    blk_sum2(s, ss, scr);
    float mm = s * (1.f / Nn);
    float vv = fmaxf(ss * (1.f / Nn) - mm * mm, 0.f);
    float rstd = rsqrtf(vv + 1e-5f);
    float scM = rstd * cvt(((const T*)p.n3w)[d]);
    float shM = cvt(((const T*)p.n3b)[d]) - mm * scM;
    const T* row = (const T*)p.row;
    float scI = st[ST_IN_SC + c], shI = st[ST_IN_SH + c];
    const T* rp = row + (size_t)b * Nn * Dn + d;
    float* tp = p.ws + WS_T + (size_t)b * Nn * Dn + d;
    float x0 = cvt(rp[(size_t)tid * Dn]) * scI + shI + m0 * scM + shM;
    float x1 = cvt(rp[(size_t)(tid + 256) * Dn]) * scI + shI + m1 * scM + shM;
    tp[(size_t)tid * Dn] = x0;
    tp[(size_t)(tid + 256) * Dn] = x1;
    __syncthreads();
    float s2 = x0 + x1, ss2 = x0 * x0 + x1 * x1;
    blk_sum2(s2, ss2, scr);
    if (tid == 0) {
        float m = s2 * (1.f / Nn);
        float v = fmaxf(ss2 * (1.f / Nn) - m * m, 0.f);
        float r = rsqrtf(v + 1e-5f);
        float sc = r * cvt(((const T*)p.f1w)[d]);
        st[ST_X_SC + c] = sc;
        st[ST_X_SH + c] = cvt(((const T*)p.f1b)[d]) - m * sc;
    }
}

// ---------------------------------------------------------------------------
// Phase 6: FFN (x normalized inline), 2 rows/block, 512 blocks.
template <typename T>
__device__ void phase6(const KP& p, float* st, float* smem) {
    int tid = threadIdx.x;
    int r0 = blockIdx.x * 2;
    int b = r0 >> 9;
    const float* t = p.ws + WS_T;
    float* outpre = p.ws + WS_OP;
    const T* w1 = (const T*)p.ffw1; const T* b1 = (const T*)p.ffb1;
    const T* w2 = (const T*)p.ffw2; const T* b2 = (const T*)p.ffb2;

    float* xl = smem;            // [2][128]
    float* hl = smem + 256;      // [2][512]
    float* red = smem + 1280;    // [2][2][128]
    {
        int r = tid >> 7, d = tid & 127;
        int c = b * 128 + d;
        xl[r * 128 + d] = t[(r0 + r) * Dn + d] * st[ST_X_SC + c] + st[ST_X_SH + c];
    }
    __syncthreads();
    {
        int f0 = tid, f1 = tid + 256;
        float a00 = 0, a10 = 0, a01 = 0, a11 = 0;
#pragma unroll 4
        for (int k = 0; k < Dn; ++k) {
            float w0 = cvt(w1[k * FHn + f0]);
            float wA = cvt(w1[k * FHn + f1]);
            a00 += xl[k] * w0;       a10 += xl[128 + k] * w0;
            a01 += xl[k] * wA;       a11 += xl[128 + k] * wA;
        }
        float bb0 = cvt(b1[f0]), bbA = cvt(b1[f1]);
        hl[f0] = fmaxf(a00 + bb0, 0.f);        hl[512 + f0] = fmaxf(a10 + bb0, 0.f);
        hl[f1] = fmaxf(a01 + bbA, 0.f);        hl[512 + f1] = fmaxf(a11 + bbA, 0.f);
    }
    __syncthreads();
    {
        int d = tid & 127, half = tid >> 7;
        int k0 = half * 256;
        float c0 = 0, c1 = 0;
#pragma unroll 8
        for (int k = k0; k < k0 + 256; ++k) {
            float w = cvt(w2[k * Dn + d]);
            c0 += hl[k] * w;
            c1 += hl[512 + k] * w;
        }
        red[half * 256 + d] = c0;  red[half * 256 + 128 + d] = c1;
    }
    __syncthreads();
    if (tid < 128) {
        float bb2 = cvt(b2[tid]);
        outpre[(r0 + 0) * Dn + tid] = xl[tid] + red[tid] + red[256 + tid] + bb2;
        outpre[(r0 + 1) * Dn + tid] = xl[128 + tid] + red[128 + tid] + red[256 + 128 + tid] + bb2;
    }
}

// ---------------------------------------------------------------------------
// Phase 7+8 fused: per-column outpre stats (local) -> cast out. 256 blocks.
template <typename T>
__device__ void phase78(const KP& p, float* smem) {
    float* scr = smem + 2560;
    int tid = threadIdx.x;
    int c = blockIdx.x;          // 0..255
    int b = c >> 7, d = c & 127;
    const float* op = p.ws + WS_OP;
    const float* sp = op + (size_t)b * Nn * Dn + d;
    float x0 = sp[(size_t)tid * Dn], x1 = sp[(size_t)(tid + 256) * Dn];
    float s = x0 + x1, ss = x0 * x0 + x1 * x1;
    blk_sum2(s, ss, scr);
    float m = s * (1.f / Nn);
    float v = fmaxf(ss * (1.f / Nn) - m * m, 0.f);
    float rstd = rsqrtf(v + 1e-5f);
    float sc = rstd * cvt(((const T*)p.f2w)[d]);
    float sh = cvt(((const T*)p.f2b)[d]) - m * sc;
    T* out = (T*)p.out + (size_t)b * Nn * Dn + d;
    out[(size_t)tid * Dn] = (T)(x0 * sc + sh);
    out[(size_t)(tid + 256) * Dn] = (T)(x1 * sc + sh);
}

// ---------------------------------------------------------------------------
// Kernel wrappers
#define PH_WRAP(name, call_bf, call_f)                                        \
__global__ __launch_bounds__(256) void name(KP p) {                           \
    __shared__ float smem[SMEM_FLOATS];                                       \
    float* st = p.ws + WS_ST; (void)st;                                       \
    if (is_bf16(p.alpha)) { call_bf; } else { call_f; }                       \
}

PH_WRAP(k_head,  phase0<bf16>(p, st, smem),  phase0<float>(p, st, smem))
PH_WRAP(k_qkveab, phase1<bf16>(p, st, smem), phase1<float>(p, st, smem))
__global__ __launch_bounds__(256) void k_kekv(KP p) {
    __shared__ float smem[SMEM_FLOATS];
    phase2(p, smem);
}
PH_WRAP(k_attn,  phase3<bf16>(p, smem),      phase3<float>(p, smem))
PH_WRAP(k_mid,   phase45<bf16>(p, st, smem), phase45<float>(p, st, smem))
PH_WRAP(k_ffn,   phase6<bf16>(p, st, smem),  phase6<float>(p, st, smem))
PH_WRAP(k_tail,  phase78<bf16>(p, smem),     phase78<float>(p, smem))

// ---------------------------------------------------------------------------
extern "C" void kernel_launch(void* const* d_in, const int* in_sizes, int n_in,
                              void* d_out, int out_size, void* d_ws, size_t ws_size,
                              hipStream_t stream) {
    KP p;
    p.row = d_in[0];  p.col = d_in[1];  p.cost = d_in[2];  p.coords = d_in[3];
    p.alpha = d_in[4];
    p.n1w = d_in[5];  p.n1b = d_in[6];  p.n2w = d_in[7];  p.n2b = d_in[8];
    p.n3w = d_in[9];  p.n3b = d_in[10]; p.f1w = d_in[11]; p.f1b = d_in[12];
    p.f2w = d_in[13]; p.f2b = d_in[14];
    p.qw = d_in[15];  p.qb = d_in[16];  p.kw = d_in[17];  p.kb = d_in[18];
    p.vw = d_in[19];  p.vb = d_in[20];  p.pw = d_in[21];  p.pb = d_in[22];
    p.mw = d_in[23];  p.mb = d_in[24];
    p.dw1 = d_in[25]; p.db1 = d_in[26]; p.dw2 = d_in[27]; p.db2 = d_in[28];
    p.aw1 = d_in[29]; p.ab1 = d_in[30]; p.aw2 = d_in[31]; p.ab2 = d_in[32];
    p.gw = d_in[33];  p.gb = d_in[34];  p.ow = d_in[35];  p.ob = d_in[36];
    p.ffw1 = d_in[37]; p.ffb1 = d_in[38]; p.ffw2 = d_in[39]; p.ffb2 = d_in[40];
    p.out = d_out;
    p.ws = (float*)d_ws;

    k_head<<<512, 256, 0, stream>>>(p);
    k_qkveab<<<512, 256, 0, stream>>>(p);
    k_kekv<<<256, 256, 0, stream>>>(p);
    k_attn<<<512, 256, 0, stream>>>(p);
    k_mid<<<256, 256, 0, stream>>>(p);
    k_ffn<<<512, 256, 0, stream>>>(p);
    k_tail<<<256, 256, 0, stream>>>(p);
}

// Round 10
// 242.393 us; speedup vs baseline: 1.0984x; 1.0984x over previous
//
#include <hip/hip_runtime.h>
#include <hip/hip_bf16.h>
#include <math.h>

// Problem constants
#define Bn  2
#define Nn  512
#define Dn  128
#define FHn 512
#define BND (Bn*Nn*Dn)   // 131072

typedef __hip_bfloat16 bf16;

__device__ __forceinline__ float cvt(float x) { return x; }
__device__ __forceinline__ float cvt(bf16 x) { return __bfloat162float(x); }
__device__ __forceinline__ float sigmoidf_(float x) { return 1.0f / (1.0f + expf(-x)); }
__device__ __forceinline__ bool is_bf16(const void* alpha) {
    return ((const unsigned short*)alpha)[0] == 0x3F80;
}

// ---------------------------------------------------------------------------
// Workspace layout (float offsets). S = one (B,N,D) f32 slab.
// eK/eKV in [j][h] layout (R8): wave-coalesced in both producer and consumer.
#define S_ 131072
#define WS_Q    (0 * S_)
#define WS_K    (1 * S_)
#define WS_V    (2 * S_)
#define WS_EK   (3 * S_)
#define WS_EKV  (4 * S_)
#define WS_EAB  (5 * S_)   // (B,N,N) f32 = 4 slabs
#define WS_MH   (1 * S_)
#define WS_T    (2 * S_)
#define WS_OP   (3 * S_)
#define WS_ST   (9 * S_)

// stats region (float offsets inside WS_ST)
#define ST_IN_SC   0      // 512: [which*256 + b*128 + d]
#define ST_IN_SH   512
#define ST_X_SC    2048
#define ST_X_SH    2304
#define ST_PRE     3072
#define P_SC       1024   // cds, cdt, cas, cat, gate_b, outlin_b, alpha (7)
#define ST_TAB     4224   // 1288 floats of piecewise-linear tables

#define TAB_ANG 644
#define TAB_N   1288

#define SMEM_FLOATS 2568   // 2560 work + 8 reduce scratch (256-thread kernels)

struct KP {
    const void *row, *col, *cost, *coords, *alpha;
    const void *n1w, *n1b, *n2w, *n2b, *n3w, *n3b, *f1w, *f1b, *f2w, *f2b;
    const void *qw, *qb, *kw, *kb, *vw, *vb, *pw, *pb, *mw, *mb;
    const void *dw1, *db1, *dw2, *db2, *aw1, *ab1, *aw2, *ab2, *gw, *gb, *ow, *ob;
    const void *ffw1, *ffb1, *ffw2, *ffb2;
    void* out;
    float* ws;
};

// ---------------------------------------------------------------------------
// Block-level reductions (256 threads). scr >= 8 floats. All threads get result.
__device__ __forceinline__ void blk_sum2(float& s, float& ss, volatile float* scr) {
#pragma unroll
    for (int off = 32; off > 0; off >>= 1) { s += __shfl_down(s, off); ss += __shfl_down(ss, off); }
    __syncthreads();
    int wave = threadIdx.x >> 6, lane = threadIdx.x & 63;
    if (lane == 0) { scr[wave] = s; scr[4 + wave] = ss; }
    __syncthreads();
    s = scr[0] + scr[1] + scr[2] + scr[3];
    ss = scr[4] + scr[5] + scr[6] + scr[7];
}

__device__ __forceinline__ float blk_sum1(float v, volatile float* scr) {
#pragma unroll
    for (int off = 32; off > 0; off >>= 1) v += __shfl_down(v, off);
    __syncthreads();
    int wave = threadIdx.x >> 6, lane = threadIdx.x & 63;
    if (lane == 0) scr[wave] = v;
    __syncthreads();
    return scr[0] + scr[1] + scr[2] + scr[3];
}

__device__ __forceinline__ float blk_max1(float v, volatile float* scr) {
#pragma unroll
    for (int off = 32; off > 0; off >>= 1) v = fmaxf(v, __shfl_down(v, off));
    __syncthreads();
    int wave = threadIdx.x >> 6, lane = threadIdx.x & 63;
    if (lane == 0) scr[wave] = v;
    __syncthreads();
    return fmaxf(fmaxf(scr[0], scr[1]), fmaxf(scr[2], scr[3]));
}

// ---------------------------------------------------------------------------
// Build piecewise-linear tables for one scalar MLP — fully parallel (R8).
template <typename T>
__device__ void build_tables(const T* w1p, const T* b1p, const T* w2p,
                             const T* owp, const T* gwp, float* gtab, float* smem) {
    int tid = threadIdx.x;
    float* W  = smem;          // 128
    float* Bb = smem + 128;
    float* U  = smem + 256;
    float* Vv = smem + 384;
    float* Tt = smem + 512;
    int* RK   = (int*)(smem + 640);   // 128 ranks
    if (tid < 128) {
        float u = 0.f, v = 0.f;
#pragma unroll 4
        for (int d = 0; d < Dn; ++d) {
            float w2 = cvt(w2p[tid * Dn + d]);
            u += w2 * cvt(owp[d]);
            v += w2 * cvt(gwp[d]);
        }
        float w = cvt(w1p[tid]), b = cvt(b1p[tid]);
        U[tid] = u; Vv[tid] = v; W[tid] = w; Bb[tid] = b;
        Tt[tid] = (w != 0.f) ? (-b / w) : 3.0e38f;
    }
    __syncthreads();
    if (tid < 128) {
        float tk = Tt[tid]; int r = 0;
        for (int j = 0; j < 128; ++j) {
            float tj = Tt[j];
            r += (tj < tk) || (tj == tk && j < tid);
        }
        RK[tid] = r;
        gtab[r] = tk;        // sorted breakpoint table (scatter by rank)
    }
    __syncthreads();
    if (tid <= 128) {
        int si = tid;
        float slS = 0, inS = 0, slT = 0, inT = 0;
        for (int k = 0; k < 128; ++k) {
            float w = W[k];
            if (w == 0.f) {
                float rb = fmaxf(Bb[k], 0.f);
                inS += rb * U[k];
                inT += rb * Vv[k];
            } else {
                bool act = (w > 0.f) ? (RK[k] < si) : (RK[k] >= si);
                if (act) {
                    slS += w * U[k];  inS += Bb[k] * U[k];
                    slT += w * Vv[k]; inT += Bb[k] * Vv[k];
                }
            }
        }
        gtab[128 + si] = slS;
        gtab[257 + si] = inS;
        gtab[386 + si] = slT;
        gtab[515 + si] = inT;
    }
}

// number of sorted breakpoints <= c, in [0,128]; 8 uniform iterations.
__device__ __forceinline__ int bsearch128(const float* T, float c) {
    int lo = 0, hi = 128;
    while (lo < hi) { int mid = (lo + hi) >> 1; if (T[mid] <= c) lo = mid + 1; else hi = mid; }
    return lo;
}

// ---------------------------------------------------------------------------
// Phase 0: input instance-norm stats (512 cols, 1/block); block 128 = scalar
// constants; blocks 129/130 = dist/angle piecewise tables.
template <typename T>
__device__ void phase0(const KP& p, float* st, float* smem) {
    float* scr = smem + 2560;
    int cid = blockIdx.x;    // 0..511
    int tid = threadIdx.x;
    {
        int which = cid >> 8, b = (cid >> 7) & 1, d = cid & 127;
        const T* src = (const T*)(which ? p.col : p.row) + (size_t)b * Nn * Dn + d;
        float x0 = cvt(src[(size_t)tid * Dn]);
        float x1 = cvt(src[(size_t)(tid + 256) * Dn]);
        float s = x0 + x1, ss = x0 * x0 + x1 * x1;
        blk_sum2(s, ss, scr);
        if (tid == 0) {
            float m = s * (1.f / Nn);
            float v = fmaxf(ss * (1.f / Nn) - m * m, 0.f);
            float rstd = rsqrtf(v + 1e-5f);
            const T* w = which ? (const T*)p.n2w : (const T*)p.n1w;
            const T* bb = which ? (const T*)p.n2b : (const T*)p.n1b;
            float sc = rstd * cvt(w[d]);
            st[ST_IN_SC + cid] = sc;
            st[ST_IN_SH + cid] = cvt(bb[d]) - m * sc;
        }
    }
    __syncthreads();
    if (cid == 128) {
        const T* db2 = (const T*)p.db2; const T* ab2 = (const T*)p.ab2;
        const T* ow = (const T*)p.ow;   const T* gw = (const T*)p.gw;
        float d2 = 0.f, a2 = 0.f, o = 0.f, g0 = 0.f, g1 = 0.f;
        if (tid < 128) {
            d2 = cvt(db2[tid]); a2 = cvt(ab2[tid]);
            o = cvt(ow[tid]); g0 = cvt(gw[tid]); g1 = cvt(gw[Dn + tid]);
        }
        float cds = d2 * o, cdt = d2 * g0, cas = a2 * o, cat = a2 * g1;
        blk_sum2(cds, cdt, scr);
        blk_sum2(cas, cat, scr);
        if (tid == 0) {
            float* pre = st + ST_PRE;
            pre[P_SC + 0] = cds; pre[P_SC + 1] = cdt;
            pre[P_SC + 2] = cas; pre[P_SC + 3] = cat;
            pre[P_SC + 4] = cvt(((const T*)p.gb)[0]);
            pre[P_SC + 5] = cvt(((const T*)p.ob)[0]);
            pre[P_SC + 6] = cvt(((const T*)p.alpha)[0]);
        }
    } else if (cid == 129) {
        build_tables<T>((const T*)p.dw1, (const T*)p.db1, (const T*)p.dw2,
                        (const T*)p.ow, (const T*)p.gw, st + ST_TAB, smem);
    } else if (cid == 130) {
        build_tables<T>((const T*)p.aw1, (const T*)p.ab1, (const T*)p.aw2,
                        (const T*)p.ow, (const T*)p.gw + Dn, st + ST_TAB + TAB_ANG, smem);
    }
}

// ---------------------------------------------------------------------------
// Phase 1: QKV for 2 rows/block, then eab (table-based) for the same 2 rows.
template <typename T>
__device__ void phase1(const KP& p, float* st, float* smem) {
    int tid = threadIdx.x;
    int r0 = blockIdx.x * 2;     // rows r0, r0+1  (0..1023)
    int b = r0 >> 9;
    const T* row = (const T*)p.row; const T* col = (const T*)p.col;
    float* ws = p.ws;
    float* Q = ws + WS_Q; float* Kraw = ws + WS_K; float* V = ws + WS_V;

    // --- QKV ---
    float* lr = smem;            // [2][128]
    float* lc = smem + 256;      // [2][128]
    float* redq = smem + 512;    // [2(half)][2(row)][128]
    float* redk = smem + 1024;
    float* redv = smem + 1536;
    {
        int r = tid >> 7, d = tid & 127;
        float scR = st[ST_IN_SC + b * 128 + d],       shR = st[ST_IN_SH + b * 128 + d];
        float scC = st[ST_IN_SC + 256 + b * 128 + d], shC = st[ST_IN_SH + 256 + b * 128 + d];
        lr[r * 128 + d] = cvt(row[(size_t)(r0 + r) * Dn + d]) * scR + shR;
        lc[r * 128 + d] = cvt(col[(size_t)(r0 + r) * Dn + d]) * scC + shC;
    }
    __syncthreads();
    {
        int h = tid & 127, half = tid >> 7;
        const T* qw = (const T*)p.qw; const T* kw = (const T*)p.kw; const T* vw = (const T*)p.vw;
        float q0 = 0, q1 = 0, ka = 0, kb_ = 0, v0 = 0, v1 = 0;
        int ks = half * 64;
#pragma unroll 8
        for (int k = ks; k < ks + 64; ++k) {
            float wq = cvt(qw[k * Dn + h]);
            float wk = cvt(kw[k * Dn + h]);
            float wv = cvt(vw[k * Dn + h]);
            q0 += lr[k] * wq;        q1 += lr[128 + k] * wq;
            ka += lc[k] * wk;        kb_ += lc[128 + k] * wk;
            v0 += lc[k] * wv;        v1 += lc[128 + k] * wv;
        }
        redq[half * 256 + h] = q0;  redq[half * 256 + 128 + h] = q1;
        redk[half * 256 + h] = ka;  redk[half * 256 + 128 + h] = kb_;
        redv[half * 256 + h] = v0;  redv[half * 256 + 128 + h] = v1;
    }
    __syncthreads();
    if (tid < 128) {
        int h = tid;
        float bq = cvt(((const T*)p.qb)[h]);
        float bk = cvt(((const T*)p.kb)[h]);
        float bv = cvt(((const T*)p.vb)[h]);
#pragma unroll
        for (int r = 0; r < 2; ++r) {
            Q[(r0 + r) * Dn + h]    = sigmoidf_(redq[r * 128 + h] + redq[256 + r * 128 + h] + bq);
            Kraw[(r0 + r) * Dn + h] = redk[r * 128 + h] + redk[256 + r * 128 + h] + bk;
            V[(r0 + r) * Dn + h]    = redv[r * 128 + h] + redv[256 + r * 128 + h] + bv;
        }
    }
    __syncthreads();

    // --- eab via piecewise-linear tables ---
    float* abv = smem;           // [512]
    float* red = smem + 512;     // [256]
    float* tab = smem + 768;     // [1288]
    const float* gtab = st + ST_TAB;
    for (int e = tid; e < TAB_N; e += 256) tab[e] = gtab[e];
    __syncthreads();
    float* eab = ws + WS_EAB;
    const float* pre = st + ST_PRE;
    float cds = pre[P_SC + 0], cdt = pre[P_SC + 1], cas = pre[P_SC + 2], cat = pre[P_SC + 3];
    float gbias = pre[P_SC + 4], obias = pre[P_SC + 5], alpha = pre[P_SC + 6];
    const T* cost = (const T*)p.cost;
    const T* coords = (const T*)p.coords;

    for (int rr = 0; rr < 2; ++rr) {
        int rowi = r0 + rr;
        int bb_ = rowi >> 9, i = rowi & 511;
        float cix = cvt(coords[((size_t)bb_ * Nn + i) * 2 + 0]);
        float ciy = cvt(coords[((size_t)bb_ * Nn + i) * 2 + 1]);
        const T* crow = cost + (size_t)bb_ * Nn * Nn + (size_t)i * Nn;
#pragma unroll
        for (int jj = 0; jj < 2; ++jj) {
            int j = tid + jj * 256;
            float c = cvt(crow[j]);
            int si = bsearch128(tab, c);
            float sd = fmaf(tab[128 + si], c, tab[257 + si]) + cds;
            float td = fmaf(tab[386 + si], c, tab[515 + si]) + cdt;
            float dx = cix - cvt(coords[((size_t)bb_ * Nn + j) * 2 + 0]);
            float dy = ciy - cvt(coords[((size_t)bb_ * Nn + j) * 2 + 1]);
            float ang = (dx == 0.f && dy == 0.f) ? 0.f : atan2f(dy, dx);
            int ai = bsearch128(tab + TAB_ANG, ang);
            float sa = fmaf(tab[TAB_ANG + 128 + ai], ang, tab[TAB_ANG + 257 + ai]) + cas;
            float ta = fmaf(tab[TAB_ANG + 386 + ai], ang, tab[TAB_ANG + 515 + ai]) + cat;
            float gv = sigmoidf_(td + ta + gbias);
            abv[j] = alpha * (gv * sd + (1.f - gv) * sa + obias);
        }
        __syncthreads();
        float m = fmaxf(abv[tid], abv[tid + 256]);
        red[tid] = m; __syncthreads();
        for (int s = 128; s > 0; s >>= 1) {
            if (tid < s) red[tid] = fmaxf(red[tid], red[tid + s]);
            __syncthreads();
        }
        m = red[0];
        __syncthreads();
        float e0 = expf(abv[tid] - m), e1 = expf(abv[tid + 256] - m);
        red[tid] = e0 + e1; __syncthreads();
        for (int s = 128; s > 0; s >>= 1) {
            if (tid < s) red[tid] += red[tid + s];
            __syncthreads();
        }
        float rsum = 1.f / red[0];
        float* orow = eab + (size_t)rowi * Nn;
        orow[tid] = expf(e0 * rsum);
        orow[tid + 256] = expf(e1 * rsum);
        __syncthreads();
    }
}

// ---------------------------------------------------------------------------
// Phase 2: K-softmax over tokens + fused eK/eKV, [j][h] layout (R8). 256 blocks.
__device__ void phase2(const KP& p, float* smem) {
    float* scr = smem + 2560;
    int tid = threadIdx.x;
    int c = blockIdx.x;          // 0..255
    int b = c >> 7, h = c & 127;
    float* ws = p.ws;
    const float* Kraw = ws + WS_K;
    const float* V = ws + WS_V;
    float* eK = ws + WS_EK;
    float* eKV = ws + WS_EKV;
    const float* kb = Kraw + (size_t)b * Nn * Dn + h;
    const float* vb = V + (size_t)b * Nn * Dn + h;
    float x0 = kb[(size_t)tid * Dn];
    float x1 = kb[(size_t)(tid + 256) * Dn];
    float mx = blk_max1(fmaxf(x0, x1), scr);
    float e0 = expf(x0 - mx), e1 = expf(x1 - mx);
    float s = blk_sum1(e0 + e1, scr);
    float rs = 1.f / s;
    size_t a0 = (size_t)b * Nn * Dn + (size_t)tid * Dn + h;
    size_t a1 = (size_t)b * Nn * Dn + (size_t)(tid + 256) * Dn + h;
    float ek0 = expf(e0 * rs), ek1 = expf(e1 * rs);
    eK[a0] = ek0;  eKV[a0] = ek0 * vb[(size_t)tid * Dn];
    eK[a1] = ek1;  eKV[a1] = ek1 * vb[(size_t)(tid + 256) * Dn];
}

// ---------------------------------------------------------------------------
// Phase 3: num/den einsums + p/mhc projections.
// 4 rows/block, 512 threads (h = tid&127, q = tid>>7 = j/k quarter), 256 blocks.
// LDS: ab[4][512] + redn[4][4][128] + redd[4][4][128] + gl[4][128] + yl[4][128]
template <typename T>
__device__ void phase3(const KP& p, float* smem) {
    int tid = threadIdx.x;
    int r0 = blockIdx.x * 4;
    int b = r0 >> 9;
    float* ws = p.ws;
    const float* eab = ws + WS_EAB;
    const float* eK = ws + WS_EK;
    const float* eKV = ws + WS_EKV;
    const float* Q = ws + WS_Q;
    float* mh = ws + WS_MH;

    float* ab   = smem;          // 2048
    float* redn = smem + 2048;   // 2048
    float* redd = smem + 4096;   // 2048
    float* gl   = smem + 6144;   // 512
    float* yl   = smem + 6656;   // 512

    {   // stage 4 rows of eab: 2048 floats = 512 float4, one per thread
        float4* ab4 = (float4*)ab;
        const float4* g4 = (const float4*)(eab + (size_t)r0 * Nn);
        ab4[tid] = g4[tid];
    }
    __syncthreads();
    int h = tid & 127, q = tid >> 7;   // q in 0..3
    {
        float num[4] = {0,0,0,0}, den[4] = {0,0,0,0};
        int j0 = q * 128;
        const float* ekb = eK + (size_t)b * Nn * Dn + h;
        const float* evb = eKV + (size_t)b * Nn * Dn + h;
#pragma unroll 4
        for (int j = j0; j < j0 + 128; ++j) {
            float ek = ekb[(size_t)j * Dn];
            float ev = evb[(size_t)j * Dn];
#pragma unroll
            for (int r = 0; r < 4; ++r) {
                num[r] += ab[r * 512 + j] * ev;
                den[r] += ab[r * 512 + j] * ek;
            }
        }
#pragma unroll
        for (int r = 0; r < 4; ++r) {
            redn[q * 512 + r * 128 + h] = num[r];
            redd[q * 512 + r * 128 + h] = den[r];
        }
    }
    __syncthreads();
    if (tid < 128) {
#pragma unroll
        for (int r = 0; r < 4; ++r) {
            float nu = redn[r * 128 + h] + redn[512 + r * 128 + h]
                     + redn[1024 + r * 128 + h] + redn[1536 + r * 128 + h];
            float de = redd[r * 128 + h] + redd[512 + r * 128 + h]
                     + redd[1024 + r * 128 + h] + redd[1536 + r * 128 + h];
            gl[r * 128 + h] = Q[(r0 + r) * Dn + h] * nu / de;
        }
    }
    __syncthreads();
    {   // Yt = G@pw + pb : k-quarter of 32
        const T* pw = (const T*)p.pw;
        float acc[4] = {0,0,0,0};
        int ks = q * 32;
#pragma unroll 8
        for (int k = ks; k < ks + 32; ++k) {
            float w = cvt(pw[k * Dn + h]);
#pragma unroll
            for (int r = 0; r < 4; ++r) acc[r] += gl[r * 128 + k] * w;
        }
#pragma unroll
        for (int r = 0; r < 4; ++r) redn[q * 512 + r * 128 + h] = acc[r];
    }
    __syncthreads();
    if (tid < 128) {
        float bp = cvt(((const T*)p.pb)[h]);
#pragma unroll
        for (int r = 0; r < 4; ++r)
            yl[r * 128 + h] = redn[r * 128 + h] + redn[512 + r * 128 + h]
                            + redn[1024 + r * 128 + h] + redn[1536 + r * 128 + h] + bp;
    }
    __syncthreads();
    {   // mh = Yt@mw + mb
        const T* mw = (const T*)p.mw;
        float acc[4] = {0,0,0,0};
        int ks = q * 32;
#pragma unroll 8
        for (int k = ks; k < ks + 32; ++k) {
            float w = cvt(mw[k * Dn + h]);
#pragma unroll
            for (int r = 0; r < 4; ++r) acc[r] += yl[r * 128 + k] * w;
        }
#pragma unroll
        for (int r = 0; r < 4; ++r) redn[q * 512 + r * 128 + h] = acc[r];
    }
    __syncthreads();
    if (tid < 128) {
        float bm = cvt(((const T*)p.mb)[h]);
#pragma unroll
        for (int r = 0; r < 4; ++r)
            mh[(r0 + r) * Dn + h] = redn[r * 128 + h] + redn[512 + r * 128 + h]
                                  + redn[1024 + r * 128 + h] + redn[1536 + r * 128 + h] + bm;
    }
}

// ---------------------------------------------------------------------------
// Phase 4+5 fused: per-column mh stats (local) -> t build -> x stats. 256 blocks.
template <typename T>
__device__ void phase45(const KP& p, float* st, float* smem) {
    float* scr = smem + 2560;
    int tid = threadIdx.x;
    int c = blockIdx.x;          // 0..255
    int b = c >> 7, d = c & 127;
    const float* mh = p.ws + WS_MH;
    const float* mp = mh + (size_t)b * Nn * Dn + d;
    float m0 = mp[(size_t)tid * Dn], m1 = mp[(size_t)(tid + 256) * Dn];
    float s = m0 + m1, ss = m0 * m0 + m1 * m1;
    blk_sum2(s, ss, scr);
    float mm = s * (1.f / Nn);
    float vv = fmaxf(ss * (1.f / Nn) - mm * mm, 0.f);
    float rstd = rsqrtf(vv + 1e-5f);
    float scM = rstd * cvt(((const T*)p.n3w)[d]);
    float shM = cvt(((const T*)p.n3b)[d]) - mm * scM;
    const T* row = (const T*)p.row;
    float scI = st[ST_IN_SC + c], shI = st[ST_IN_SH + c];
    const T* rp = row + (size_t)b * Nn * Dn + d;
    float* tp = p.ws + WS_T + (size_t)b * Nn * Dn + d;
    float x0 = cvt(rp[(size_t)tid * Dn]) * scI + shI + m0 * scM + shM;
    float x1 = cvt(rp[(size_t)(tid + 256) * Dn]) * scI + shI + m1 * scM + shM;
    tp[(size_t)tid * Dn] = x0;
    tp[(size_t)(tid + 256) * Dn] = x1;
    __syncthreads();
    float s2 = x0 + x1, ss2 = x0 * x0 + x1 * x1;
    blk_sum2(s2, ss2, scr);
    if (tid == 0) {
        float m = s2 * (1.f / Nn);
        float v = fmaxf(ss2 * (1.f / Nn) - m * m, 0.f);
        float r = rsqrtf(v + 1e-5f);
        float sc = r * cvt(((const T*)p.f1w)[d]);
        st[ST_X_SC + c] = sc;
        st[ST_X_SH + c] = cvt(((const T*)p.f1b)[d]) - m * sc;
    }
}

// ---------------------------------------------------------------------------
// Phase 6: FFN (x normalized inline). 4 rows/block, 512 threads, 256 blocks.
// pass1: thread owns hidden col f = tid (exactly 512). pass2: (d, quarter).
template <typename T>
__device__ void phase6(const KP& p, float* st, float* smem) {
    int tid = threadIdx.x;
    int r0 = blockIdx.x * 4;
    int b = r0 >> 9;
    const float* t = p.ws + WS_T;
    float* outpre = p.ws + WS_OP;
    const T* w1 = (const T*)p.ffw1; const T* b1 = (const T*)p.ffb1;
    const T* w2 = (const T*)p.ffw2; const T* b2 = (const T*)p.ffb2;

    float* xl = smem;            // [4][128] = 512
    float* hl = smem + 512;      // [4][512] = 2048
    float* red = smem + 2560;    // [4(q)][4(r)][128] = 2048
    {
        int r = tid >> 7, d = tid & 127;
        int c = b * 128 + d;
        xl[r * 128 + d] = t[(r0 + r) * Dn + d] * st[ST_X_SC + c] + st[ST_X_SH + c];
    }
    __syncthreads();
    {
        int f = tid;
        float a[4] = {0,0,0,0};
#pragma unroll 4
        for (int k = 0; k < Dn; ++k) {
            float w = cvt(w1[k * FHn + f]);
#pragma unroll
            for (int r = 0; r < 4; ++r) a[r] += xl[r * 128 + k] * w;
        }
        float bb1 = cvt(b1[f]);
#pragma unroll
        for (int r = 0; r < 4; ++r) hl[r * 512 + f] = fmaxf(a[r] + bb1, 0.f);
    }
    __syncthreads();
    {
        int d = tid & 127, q = tid >> 7;
        int k0 = q * 128;
        float a[4] = {0,0,0,0};
#pragma unroll 8
        for (int k = k0; k < k0 + 128; ++k) {
            float w = cvt(w2[k * Dn + d]);
#pragma unroll
            for (int r = 0; r < 4; ++r) a[r] += hl[r * 512 + k] * w;
        }
#pragma unroll
        for (int r = 0; r < 4; ++r) red[q * 512 + r * 128 + d] = a[r];
    }
    __syncthreads();
    if (tid < 128) {
        float bb2 = cvt(b2[tid]);
#pragma unroll
        for (int r = 0; r < 4; ++r) {
            float sum = red[r * 128 + tid] + red[512 + r * 128 + tid]
                      + red[1024 + r * 128 + tid] + red[1536 + r * 128 + tid];
            outpre[(r0 + r) * Dn + tid] = xl[r * 128 + tid] + sum + bb2;
        }
    }
}

// ---------------------------------------------------------------------------
// Phase 7+8 fused: per-column outpre stats (local) -> cast out. 256 blocks.
template <typename T>
__device__ void phase78(const KP& p, float* smem) {
    float* scr = smem + 2560;
    int tid = threadIdx.x;
    int c = blockIdx.x;          // 0..255
    int b = c >> 7, d = c & 127;
    const float* op = p.ws + WS_OP;
    const float* sp = op + (size_t)b * Nn * Dn + d;
    float x0 = sp[(size_t)tid * Dn], x1 = sp[(size_t)(tid + 256) * Dn];
    float s = x0 + x1, ss = x0 * x0 + x1 * x1;
    blk_sum2(s, ss, scr);
    float m = s * (1.f / Nn);
    float v = fmaxf(ss * (1.f / Nn) - m * m, 0.f);
    float rstd = rsqrtf(v + 1e-5f);
    float sc = rstd * cvt(((const T*)p.f2w)[d]);
    float sh = cvt(((const T*)p.f2b)[d]) - m * sc;
    T* out = (T*)p.out + (size_t)b * Nn * Dn + d;
    out[(size_t)tid * Dn] = (T)(x0 * sc + sh);
    out[(size_t)(tid + 256) * Dn] = (T)(x1 * sc + sh);
}

// ---------------------------------------------------------------------------
// Kernel wrappers
#define PH_WRAP(name, call_bf, call_f)                                        \
__global__ __launch_bounds__(256) void name(KP p) {                           \
    __shared__ float smem[SMEM_FLOATS];                                       \
    float* st = p.ws + WS_ST; (void)st;                                       \
    if (is_bf16(p.alpha)) { call_bf; } else { call_f; }                       \
}

PH_WRAP(k_head,  phase0<bf16>(p, st, smem),  phase0<float>(p, st, smem))
PH_WRAP(k_qkveab, phase1<bf16>(p, st, smem), phase1<float>(p, st, smem))
__global__ __launch_bounds__(256) void k_kekv(KP p) {
    __shared__ float smem[SMEM_FLOATS];
    phase2(p, smem);
}
__global__ __launch_bounds__(512) void k_attn(KP p) {
    __shared__ float smem[7168];   // 28 KB
    if (is_bf16(p.alpha)) phase3<bf16>(p, smem);
    else                  phase3<float>(p, smem);
}
PH_WRAP(k_mid,   phase45<bf16>(p, st, smem), phase45<float>(p, st, smem))
__global__ __launch_bounds__(512) void k_ffn(KP p) {
    __shared__ float smem[4608];   // 18 KB
    float* st = p.ws + WS_ST;
    if (is_bf16(p.alpha)) phase6<bf16>(p, st, smem);
    else                  phase6<float>(p, st, smem);
}
PH_WRAP(k_tail,  phase78<bf16>(p, smem),     phase78<float>(p, smem))

// ---------------------------------------------------------------------------
extern "C" void kernel_launch(void* const* d_in, const int* in_sizes, int n_in,
                              void* d_out, int out_size, void* d_ws, size_t ws_size,
                              hipStream_t stream) {
    KP p;
    p.row = d_in[0];  p.col = d_in[1];  p.cost = d_in[2];  p.coords = d_in[3];
    p.alpha = d_in[4];
    p.n1w = d_in[5];  p.n1b = d_in[6];  p.n2w = d_in[7];  p.n2b = d_in[8];
    p.n3w = d_in[9];  p.n3b = d_in[10]; p.f1w = d_in[11]; p.f1b = d_in[12];
    p.f2w = d_in[13]; p.f2b = d_in[14];
    p.qw = d_in[15];  p.qb = d_in[16];  p.kw = d_in[17];  p.kb = d_in[18];
    p.vw = d_in[19];  p.vb = d_in[20];  p.pw = d_in[21];  p.pb = d_in[22];
    p.mw = d_in[23];  p.mb = d_in[24];
    p.dw1 = d_in[25]; p.db1 = d_in[26]; p.dw2 = d_in[27]; p.db2 = d_in[28];
    p.aw1 = d_in[29]; p.ab1 = d_in[30]; p.aw2 = d_in[31]; p.ab2 = d_in[32];
    p.gw = d_in[33];  p.gb = d_in[34];  p.ow = d_in[35];  p.ob = d_in[36];
    p.ffw1 = d_in[37]; p.ffb1 = d_in[38]; p.ffw2 = d_in[39]; p.ffb2 = d_in[40];
    p.out = d_out;
    p.ws = (float*)d_ws;

    k_head<<<512, 256, 0, stream>>>(p);
    k_qkveab<<<512, 256, 0, stream>>>(p);
    k_kekv<<<256, 256, 0, stream>>>(p);
    k_attn<<<256, 512, 0, stream>>>(p);
    k_mid<<<256, 256, 0, stream>>>(p);
    k_ffn<<<256, 512, 0, stream>>>(p);
    k_tail<<<256, 256, 0, stream>>>(p);
}